// Round 1
// baseline (1017.970 us; speedup 1.0000x reference)
//
#include <hip/hip_runtime.h>
#include <hip/hip_bf16.h>
#include <stdint.h>

// Problem constants (exact divisions, no bounds checks needed)
#define M_TOT 16384   // 8*2048 rows of x
#define N_TOT 4096    // output features
#define K_TOT 4096    // input features
#define BM 128
#define BN 128
#define BK 64
#define LDK 72        // LDS row pitch (+8 bf16 pad -> 144B stride, breaks 128B bank aliasing)

typedef unsigned short ushort_t;
typedef __attribute__((ext_vector_type(8))) short short8;   // 8 bf16 = 4 VGPRs (MFMA A/B frag)
typedef __attribute__((ext_vector_type(4))) float f32x4;    // MFMA C/D frag

// RNE fp32 -> bf16 (3 int ops; inputs are finite randoms, no NaN path needed)
__device__ __forceinline__ ushort_t f2bf(float f) {
  union { float f; uint32_t u; } v; v.f = f;
  uint32_t u = v.u;
  return (ushort_t)((u + 0x7FFFu + ((u >> 16) & 1u)) >> 16);
}

// Unpack 6-bit weights: per group of 3 ints -> 4 values (p0&63, (p0>>6)&63, p1&63, p2&63)
__global__ void dequant_w_kernel(const int* __restrict__ q,
                                 const float* __restrict__ scale,
                                 const float* __restrict__ zp,
                                 ushort_t* __restrict__ wbf) {
  int g = blockIdx.x * 256 + threadIdx.x;      // 0 .. 4096*1024-1
  int n   = g >> 10;
  int grp = g & 1023;
  const int* p = q + (size_t)n * 3072 + grp * 3;
  int p0 = p[0], p1 = p[1], p2 = p[2];
  float s = scale[n], z = zp[n];
  ushort4 o;
  o.x = f2bf(((float)(p0 & 63)        - z) * s);
  o.y = f2bf(((float)((p0 >> 6) & 63) - z) * s);
  o.z = f2bf(((float)(p1 & 63)        - z) * s);
  o.w = f2bf(((float)(p2 & 63)        - z) * s);
  *(ushort4*)(wbf + (size_t)n * 4096 + grp * 4) = o;
}

__global__ void convert_x_kernel(const float* __restrict__ x,
                                 ushort_t* __restrict__ xbf) {
  size_t i = (size_t)blockIdx.x * 256 + threadIdx.x;   // float4 chunk index
  float4 v = ((const float4*)x)[i];
  ushort4 o;
  o.x = f2bf(v.x); o.y = f2bf(v.y); o.z = f2bf(v.z); o.w = f2bf(v.w);
  ((ushort4*)xbf)[i] = o;
}

// C[m][n] = sum_k A[m][k] * W[n][k] + bias[n]
// 128x128 tile, BK=64, 4 waves in 2x2, each wave 4x4 grid of 16x16x32 bf16 MFMA.
template <bool AF32>
__global__ __launch_bounds__(256, 2)
void gemm_kernel(const void* __restrict__ Aptr,
                 const ushort_t* __restrict__ W,     // [N][K] bf16 (B^T layout)
                 const float* __restrict__ bias,
                 float* __restrict__ out) {
  __shared__ ushort_t Ab[BM * LDK];
  __shared__ ushort_t Bb[BN * LDK];

  const int tid = threadIdx.x;
  const int bn = blockIdx.x;            // 0..31
  const int bm = blockIdx.y;            // 0..127
  const int w  = tid >> 6;
  const int l  = tid & 63;
  const int wr = (w >> 1) * 64;         // wave row origin in tile
  const int wc = (w & 1) * 64;          // wave col origin in tile
  const int lr = l & 15;                // A-row / B-col within 16-tile
  const int lq = l >> 4;                // k-quad

  f32x4 zero = {0.f, 0.f, 0.f, 0.f};
  f32x4 acc[4][4];
#pragma unroll
  for (int i = 0; i < 4; ++i)
#pragma unroll
    for (int j = 0; j < 4; ++j) acc[i][j] = zero;

  const size_t aRowBase = (size_t)bm * BM;
  const size_t bRowBase = (size_t)bn * BN;

  for (int k0 = 0; k0 < K_TOT; k0 += BK) {
    // ---- stage A tile (128 x 64) ----
    if (AF32) {
      const float* Ag = (const float*)Aptr + aRowBase * K_TOT + k0;
#pragma unroll
      for (int i = 0; i < 8; ++i) {
        int id = tid + i * 256;          // 0..2047, one float4 each
        int r = id >> 4;                 // 0..127
        int c = (id & 15) << 2;          // 0..60
        float4 v = *(const float4*)(Ag + (size_t)r * K_TOT + c);
        ushort4 o;
        o.x = f2bf(v.x); o.y = f2bf(v.y); o.z = f2bf(v.z); o.w = f2bf(v.w);
        *(ushort4*)(&Ab[r * LDK + c]) = o;
      }
    } else {
      const ushort_t* Ag = (const ushort_t*)Aptr + aRowBase * K_TOT + k0;
#pragma unroll
      for (int i = 0; i < 4; ++i) {
        int id = tid + i * 256;          // 0..1023, 8 bf16 each
        int r = id >> 3;                 // 0..127
        int c = (id & 7) << 3;           // 0..56
        float4 v = *(const float4*)(Ag + (size_t)r * K_TOT + c);
        *(float4*)(&Ab[r * LDK + c]) = v;
      }
    }
    // ---- stage B tile (128 x 64) from bf16 weights ----
    {
      const ushort_t* Bg = W + bRowBase * K_TOT + k0;
#pragma unroll
      for (int i = 0; i < 4; ++i) {
        int id = tid + i * 256;
        int r = id >> 3;
        int c = (id & 7) << 3;
        float4 v = *(const float4*)(Bg + (size_t)r * K_TOT + c);
        *(float4*)(&Bb[r * LDK + c]) = v;
      }
    }
    __syncthreads();

    // ---- compute: 2 k-steps of 32, 16 MFMA each ----
#pragma unroll
    for (int kk = 0; kk < BK; kk += 32) {
      short8 af[4], bfr[4];
#pragma unroll
      for (int i = 0; i < 4; ++i)
        af[i] = *(const short8*)(&Ab[(wr + i * 16 + lr) * LDK + kk + lq * 8]);
#pragma unroll
      for (int j = 0; j < 4; ++j)
        bfr[j] = *(const short8*)(&Bb[(wc + j * 16 + lr) * LDK + kk + lq * 8]);
#pragma unroll
      for (int i = 0; i < 4; ++i)
#pragma unroll
        for (int j = 0; j < 4; ++j)
          acc[i][j] = __builtin_amdgcn_mfma_f32_16x16x32_bf16(af[i], bfr[j], acc[i][j], 0, 0, 0);
    }
    __syncthreads();
  }

  // ---- epilogue: C/D layout col=lane&15, row=(lane>>4)*4+reg ----
  float bv[4];
#pragma unroll
  for (int j = 0; j < 4; ++j)
    bv[j] = bias[bn * BN + wc + j * 16 + lr];

#pragma unroll
  for (int i = 0; i < 4; ++i) {
    int m0 = bm * BM + wr + i * 16 + lq * 4;
#pragma unroll
    for (int j = 0; j < 4; ++j) {
      int n0 = bn * BN + wc + j * 16 + lr;
      float* po = out + (size_t)m0 * N_TOT + n0;
#pragma unroll
      for (int r = 0; r < 4; ++r)
        po[(size_t)r * N_TOT] = acc[i][j][r] + bv[j];
    }
  }
}

extern "C" void kernel_launch(void* const* d_in, const int* in_sizes, int n_in,
                              void* d_out, int out_size, void* d_ws, size_t ws_size,
                              hipStream_t stream) {
  const float* x     = (const float*)d_in[0];   // (8,2048,4096) fp32
  const int*   qw    = (const int*)d_in[1];     // (4096,3072) int32
  const float* scale = (const float*)d_in[2];   // (4096,1)
  const float* zp    = (const float*)d_in[3];   // (4096,1)
  const float* bias  = (const float*)d_in[4];   // (4096,)
  float* out = (float*)d_out;

  const size_t WBF = (size_t)N_TOT * K_TOT * sizeof(ushort_t);  // 33.5 MB
  const size_t XBF = (size_t)M_TOT * K_TOT * sizeof(ushort_t);  // 134 MB
  ushort_t* wbf = (ushort_t*)d_ws;

  // d_ws is re-poisoned before every call -> recompute every call (required anyway).
  dequant_w_kernel<<<(N_TOT * 1024) / 256, 256, 0, stream>>>(qw, scale, zp, wbf);

  dim3 grid(N_TOT / BN, M_TOT / BM);   // 32 x 128 = 4096 blocks
  if (ws_size >= WBF + XBF) {
    ushort_t* xbf = (ushort_t*)((char*)d_ws + WBF);
    convert_x_kernel<<<(size_t)M_TOT * K_TOT / 4 / 256, 256, 0, stream>>>(x, xbf);
    gemm_kernel<false><<<grid, 256, 0, stream>>>(xbf, wbf, bias, out);
  } else {
    // ws only fits weights: convert x on the fly during A staging
    gemm_kernel<true><<<grid, 256, 0, stream>>>(x, wbf, bias, out);
  }
}